// Round 1
// baseline (380.190 us; speedup 1.0000x reference)
//
#include <hip/hip_runtime.h>

// ---------------- types ----------------
typedef short           s16x8 __attribute__((ext_vector_type(8)));
typedef unsigned short  u16;
typedef unsigned short  u16x8 __attribute__((ext_vector_type(8)));
typedef float           f32x4 __attribute__((ext_vector_type(4)));

// ---------------- dims ----------------
#define DB   8192
#define DI   256
#define DH   1024
#define D4H  4096
#define KXH  1280   // I + H

// ---------------- helpers ----------------
__device__ __forceinline__ u16 f2bf(float f) {
    unsigned u = __float_as_uint(f);
    u = (u + 0x7FFFu + ((u >> 16) & 1u)) >> 16;
    return (u16)u;
}
__device__ __forceinline__ float bf2f(u16 v) {
    return __uint_as_float(((unsigned)v) << 16);
}
__device__ __forceinline__ float rcp_(float x) { return __builtin_amdgcn_rcpf(x); }
__device__ __forceinline__ float sigmoid_(float x) {
    x = fminf(fmaxf(x, -30.f), 30.f);
    return rcp_(1.0f + __expf(-x));
}
__device__ __forceinline__ float tanh_(float x) {
    x = fminf(fmaxf(x, -15.f), 15.f);
    float e = __expf(2.0f * x);
    return (e - 1.0f) * rcp_(e + 1.0f);
}
__device__ __forceinline__ void gload16(const void* g, void* l) {
    __builtin_amdgcn_global_load_lds(
        (const __attribute__((address_space(1))) unsigned int*)g,
        (__attribute__((address_space(3))) unsigned int*)l, 16, 0, 0);
}

// ---------------- GEMM core ----------------
// C[128x128] tile = A[m0.., K] * Bw[n0.., K]^T   (both bf16, K-contiguous rows)
// 256 threads = 4 waves in 2x2; each wave 64x64 via 4x4 frags of 16x16x32 MFMA.
// LDS tiles [128][64] bf16, XOR-swizzled (c8 ^= row&7) on both stage-source and
// ds_read so ds_read_b128 is bank-conflict-free. Staged via global_load_lds(16B).
template<int KTOT>
__device__ __forceinline__ void gemm_tile(
    const u16* __restrict__ A, int lda,
    const u16* __restrict__ Bw, int ldb,
    int m0, int n0, u16* As, u16* Bs, f32x4 acc[4][4])
{
    const int t    = threadIdx.x;
    const int lane = t & 63;
    const int w    = t >> 6;
    const int wrr  = (w >> 1) * 64;
    const int wcc  = (w & 1) * 64;

    // staging: slot idx = q*256 + t ; r = idx>>3 ; c8 = idx&7 ; src c8 ^= r&7
    const int rr  = t >> 3;                 // 0..31  (+ q*32)
    const int sc8 = (t & 7) ^ (rr & 7);
    const u16* gA = A  + (size_t)(m0 + rr) * lda + sc8 * 8;
    const u16* gB = Bw + (size_t)(n0 + rr) * ldb + sc8 * 8;
    u16* lA = As + (size_t)w * 64 * 8;      // wave-uniform LDS base (+q*2048 elems)
    u16* lB = Bs + (size_t)w * 64 * 8;

    const int l15 = lane & 15;
    const int lg  = lane >> 4;
    const int swz = l15 & 7;
    const char* cA = (const char*)As;
    const char* cB = (const char*)Bs;
    const int roA = (wrr + l15) * 128;      // row byte offset (128 B rows)
    const int roB = (wcc + l15) * 128;
    const int c0  = ((0 + lg) ^ swz) * 16;  // ks=0 swizzled 16B window
    const int c1  = ((4 + lg) ^ swz) * 16;  // ks=1

    for (int kt = 0; kt < KTOT; kt += 64) {
#pragma unroll
        for (int q = 0; q < 4; ++q)
            gload16(gA + (size_t)q * 32 * lda, lA + q * 2048);
#pragma unroll
        for (int q = 0; q < 4; ++q)
            gload16(gB + (size_t)q * 32 * ldb, lB + q * 2048);
        gA += 64; gB += 64;
        __syncthreads();   // compiler drains vmcnt before s_barrier

#pragma unroll
        for (int ks = 0; ks < 2; ++ks) {
            const int cc = ks ? c1 : c0;
            s16x8 av[4], bv[4];
#pragma unroll
            for (int mi = 0; mi < 4; ++mi)
                av[mi] = *(const s16x8*)(cA + roA + mi * 2048 + cc);
#pragma unroll
            for (int ni = 0; ni < 4; ++ni)
                bv[ni] = *(const s16x8*)(cB + roB + ni * 2048 + cc);
#pragma unroll
            for (int mi = 0; mi < 4; ++mi)
#pragma unroll
                for (int ni = 0; ni < 4; ++ni)
                    acc[mi][ni] = __builtin_amdgcn_mfma_f32_16x16x32_bf16(
                        av[mi], bv[ni], acc[mi][ni], 0, 0, 0);
        }
        __syncthreads();
    }
}

#define GEMM_PROLOGUE()                                            \
    __shared__ u16 As[128 * 64], Bs[128 * 64];                     \
    f32x4 acc[4][4];                                               \
    {   f32x4 z4 = {0.f, 0.f, 0.f, 0.f};                           \
        _Pragma("unroll") for (int i = 0; i < 4; ++i)              \
        _Pragma("unroll") for (int j = 0; j < 4; ++j)              \
            acc[i][j] = z4; }                                      \
    const int m0 = blockIdx.x * 128, n0 = blockIdx.y * 128;        \
    const int lane = threadIdx.x & 63, w = threadIdx.x >> 6;       \
    const int wrr = (w >> 1) * 64, wcc = (w & 1) * 64;             \
    const int l15 = lane & 15, lg = lane >> 4;

// D[m][n]: m = m0+wrr+mi*16+lg*4+r ; n = n0+wcc+ni*16+l15   (verified m89/m91)
#define EPILOGUE_LOOP(BODY)                                        \
    _Pragma("unroll") for (int mi = 0; mi < 4; ++mi)               \
    _Pragma("unroll") for (int ni = 0; ni < 4; ++ni)               \
    _Pragma("unroll") for (int r = 0; r < 4; ++r) {                \
        const int m = m0 + wrr + mi * 16 + lg * 4 + r;             \
        const int n = n0 + wcc + ni * 16 + l15;                    \
        float v = acc[mi][ni][r];                                  \
        BODY                                                       \
    }

// ---------------- GEMM kernels ----------------
__global__ __launch_bounds__(256) void k_gemm_gates(
    const u16* __restrict__ xh, const u16* __restrict__ Wg, u16* __restrict__ gates)
{
    GEMM_PROLOGUE();
    gemm_tile<KXH>(xh, KXH, Wg, KXH, m0, n0, As, Bs, acc);
    EPILOGUE_LOOP({ gates[(size_t)m * D4H + n] = f2bf(v); })
}

__global__ __launch_bounds__(256) void k_gemm_z(
    const u16* __restrict__ Ay, const u16* __restrict__ W1z,
    const float* __restrict__ wt, const float* __restrict__ b1,
    const float* __restrict__ t0p, const float* __restrict__ t1p, float alpha,
    u16* __restrict__ z)
{
    GEMM_PROLOGUE();
    gemm_tile<DH>(Ay, DH, W1z, DH, m0, n0, As, Bs, acc);
    const float t0v = *t0p;
    const float tv  = t0v + alpha * (*t1p - t0v);
    EPILOGUE_LOOP({
        float zz = tanh_(v + b1[n] + tv * wt[n]);
        z[(size_t)m * DH + n] = f2bf(zz);
    })
}

template<int STAGE>
__global__ __launch_bounds__(256) void k_gemm_k(
    const u16* __restrict__ zin, const u16* __restrict__ W2b,
    const float* __restrict__ b2, const u16* __restrict__ htl,
    const float* __restrict__ t0p, const float* __restrict__ t1p,
    u16* __restrict__ yout, float* __restrict__ hout)
{
    GEMM_PROLOGUE();
    gemm_tile<DH>(zin, DH, W2b, DH, m0, n0, As, Bs, acc);
    const float dtv = *t1p - *t0p;
    EPILOGUE_LOOP({
        float kv = v + b2[n];
        size_t idx = (size_t)m * DH + n;
        float ht = bf2f(htl[idx]);
        if (STAGE == 1) {
            yout[idx] = f2bf(ht + 0.5f * dtv * kv);
            hout[idx] = ht + (dtv * (1.0f / 6.0f)) * kv;   // init (no read)
        } else if (STAGE == 2) {
            yout[idx] = f2bf(ht + 0.5f * dtv * kv);
            hout[idx] += (dtv * (1.0f / 3.0f)) * kv;
        } else if (STAGE == 3) {
            yout[idx] = f2bf(ht + dtv * kv);
            hout[idx] += (dtv * (1.0f / 3.0f)) * kv;
        } else {
            hout[idx] += (dtv * (1.0f / 6.0f)) * kv;
        }
    })
}

// ---------------- prep / elementwise kernels ----------------
__global__ __launch_bounds__(256) void k_prep_wg(
    const float* __restrict__ Wih, const float* __restrict__ Whh, u16* __restrict__ Wg)
{
    int idx = blockIdx.x * 256 + threadIdx.x;           // one per 8 elems
    if (idx >= D4H * (KXH / 8)) return;
    int n  = idx / (KXH / 8);
    int k8 = idx - n * (KXH / 8);
    const float* s = (k8 < DI / 8) ? (Wih + (size_t)n * DI + k8 * 8)
                                   : (Whh + (size_t)n * DH + (k8 - DI / 8) * 8);
    f32x4 x0 = *(const f32x4*)s;
    f32x4 x1 = *(const f32x4*)(s + 4);
    u16x8 o;
#pragma unroll
    for (int e = 0; e < 4; ++e) { o[e] = f2bf(x0[e]); o[e + 4] = f2bf(x1[e]); }
    *(u16x8*)(Wg + (size_t)idx * 8) = o;
}

__global__ __launch_bounds__(256) void k_prep_xh(
    const float* __restrict__ x, const float* __restrict__ h, u16* __restrict__ xh)
{
    int idx = blockIdx.x * 256 + threadIdx.x;
    if (idx >= DB * (KXH / 8)) return;
    int b  = idx / (KXH / 8);
    int k8 = idx - b * (KXH / 8);
    const float* s = (k8 < DI / 8) ? (x + (size_t)b * DI + k8 * 8)
                                   : (h + (size_t)b * DH + (k8 - DI / 8) * 8);
    f32x4 x0 = *(const f32x4*)s;
    f32x4 x1 = *(const f32x4*)(s + 4);
    u16x8 o;
#pragma unroll
    for (int e = 0; e < 4; ++e) { o[e] = f2bf(x0[e]); o[e + 4] = f2bf(x1[e]); }
    *(u16x8*)(xh + (size_t)idx * 8) = o;
}

__global__ __launch_bounds__(256) void k_prep_w1(
    const float* __restrict__ W1, u16* __restrict__ W1z, float* __restrict__ wt)
{
    int idx = blockIdx.x * 256 + threadIdx.x;
    const int rows = DH * (DH / 8);
    if (idx < rows) {
        int n = idx >> 7, k8 = idx & 127;
        const float* s = W1 + (size_t)n * (DH + 1) + k8 * 8;   // stride 1025: scalar loads
        u16x8 o;
#pragma unroll
        for (int e = 0; e < 8; ++e) o[e] = f2bf(s[e]);
        *(u16x8*)(W1z + (size_t)idx * 8) = o;
    } else if (idx < rows + DH / 8) {
        int j = idx - rows;
#pragma unroll
        for (int e = 0; e < 8; ++e) {
            int n = j * 8 + e;
            wt[n] = W1[(size_t)n * (DH + 1) + DH];
        }
    }
}

__global__ __launch_bounds__(256) void k_prep_w2(
    const float* __restrict__ W2, u16* __restrict__ W2b)
{
    int idx = blockIdx.x * 256 + threadIdx.x;
    if (idx >= DH * (DH / 8)) return;
    const float* s = W2 + (size_t)idx * 8;
    f32x4 x0 = *(const f32x4*)s;
    f32x4 x1 = *(const f32x4*)(s + 4);
    u16x8 o;
#pragma unroll
    for (int e = 0; e < 4; ++e) { o[e] = f2bf(x0[e]); o[e + 4] = f2bf(x1[e]); }
    *(u16x8*)(W2b + (size_t)idx * 8) = o;
}

__global__ __launch_bounds__(256) void k_lstm_act(
    const u16* __restrict__ gates, const float* __restrict__ c,
    const float* __restrict__ bih, const float* __restrict__ bhh,
    float* __restrict__ outc, u16* __restrict__ htl)
{
    int idx = blockIdx.x * 256 + threadIdx.x;
    if (idx >= DB * (DH / 8)) return;
    int b = idx >> 7;
    int j = (idx & 127) * 8;
    const u16* gb = gates + (size_t)b * D4H;
    u16x8 gi = *(const u16x8*)(gb + j);
    u16x8 gf = *(const u16x8*)(gb + DH + j);
    u16x8 gg = *(const u16x8*)(gb + 2 * DH + j);
    u16x8 go = *(const u16x8*)(gb + 3 * DH + j);
    f32x4 cv0 = *(const f32x4*)(c + (size_t)b * DH + j);
    f32x4 cv1 = *(const f32x4*)(c + (size_t)b * DH + j + 4);
    float co[8]; u16x8 ho;
#pragma unroll
    for (int e = 0; e < 8; ++e) {
        float iv = bf2f(gi[e]) + bih[j + e]          + bhh[j + e];
        float fv = bf2f(gf[e]) + bih[DH + j + e]     + bhh[DH + j + e];
        float gv = bf2f(gg[e]) + bih[2 * DH + j + e] + bhh[2 * DH + j + e];
        float ov = bf2f(go[e]) + bih[3 * DH + j + e] + bhh[3 * DH + j + e];
        float cvv = (e < 4) ? cv0[e] : cv1[e - 4];
        float cn = sigmoid_(fv) * cvv + sigmoid_(iv) * tanh_(gv);
        co[e] = cn;
        ho[e] = f2bf(sigmoid_(ov) * tanh_(cn));
    }
    f32x4 o0 = {co[0], co[1], co[2], co[3]};
    f32x4 o1 = {co[4], co[5], co[6], co[7]};
    *(f32x4*)(outc + (size_t)b * DH + j)     = o0;
    *(f32x4*)(outc + (size_t)b * DH + j + 4) = o1;
    *(u16x8*)(htl + (size_t)b * DH + j) = ho;
}

// ---------------- launch ----------------
extern "C" void kernel_launch(void* const* d_in, const int* in_sizes, int n_in,
                              void* d_out, int out_size, void* d_ws, size_t ws_size,
                              hipStream_t stream)
{
    (void)in_sizes; (void)n_in; (void)out_size;
    const float* x_t = (const float*)d_in[0];
    const float* hin = (const float*)d_in[1];
    const float* cin = (const float*)d_in[2];
    const float* t0p = (const float*)d_in[3];
    const float* t1p = (const float*)d_in[4];
    const float* Wih = (const float*)d_in[5];
    const float* Whh = (const float*)d_in[6];
    const float* bih = (const float*)d_in[7];
    const float* bhh = (const float*)d_in[8];
    const float* W1  = (const float*)d_in[9];
    const float* b1  = (const float*)d_in[10];
    const float* W2  = (const float*)d_in[11];
    const float* b2  = (const float*)d_in[12];

    char* ws = (char*)d_ws;
    size_t off = 0;
    u16*   Wg    = (u16*)(ws + off);  off += (size_t)D4H * KXH * 2;  // 10.5 MB
    u16*   W1z   = (u16*)(ws + off);  off += (size_t)DH * DH * 2;    //  2.1 MB
    u16*   W2b   = (u16*)(ws + off);  off += (size_t)DH * DH * 2;    //  2.1 MB
    float* wt    = (float*)(ws + off); off += (size_t)DH * 4;
    u16*   xh    = (u16*)(ws + off);  off += (size_t)DB * KXH * 2;   // 21.0 MB
    u16*   gates = (u16*)(ws + off);  off += (size_t)DB * D4H * 2;   // 67.1 MB
    u16*   htl   = (u16*)(ws + off);  off += (size_t)DB * DH * 2;    // 16.8 MB
    u16*   ybuf  = (u16*)(ws + off);  off += (size_t)DB * DH * 2;    // 16.8 MB
    u16*   zbuf  = (u16*)(ws + off);  off += (size_t)DB * DH * 2;    // 16.8 MB
    if (ws_size < off) return;  // insufficient workspace: fail validation cleanly

    float* outh = (float*)d_out;
    float* outc = outh + (size_t)DB * DH;

    k_prep_wg<<<(D4H * (KXH / 8) + 255) / 256, 256, 0, stream>>>(Wih, Whh, Wg);
    k_prep_w1<<<(DH * (DH / 8) + DH / 8 + 255) / 256, 256, 0, stream>>>(W1, W1z, wt);
    k_prep_w2<<<(DH * (DH / 8) + 255) / 256, 256, 0, stream>>>(W2, W2b);
    k_prep_xh<<<(DB * (KXH / 8) + 255) / 256, 256, 0, stream>>>(x_t, hin, xh);

    k_gemm_gates<<<dim3(DB / 128, D4H / 128), 256, 0, stream>>>(xh, Wg, gates);
    k_lstm_act<<<(DB * (DH / 8) + 255) / 256, 256, 0, stream>>>(gates, cin, bih, bhh, outc, htl);

    dim3 g(DB / 128, DH / 128);
    k_gemm_z<<<g, 256, 0, stream>>>(htl,  W1z, wt, b1, t0p, t1p, 0.0f, zbuf);
    k_gemm_k<1><<<g, 256, 0, stream>>>(zbuf, W2b, b2, htl, t0p, t1p, ybuf, outh);
    k_gemm_z<<<g, 256, 0, stream>>>(ybuf, W1z, wt, b1, t0p, t1p, 0.5f, zbuf);
    k_gemm_k<2><<<g, 256, 0, stream>>>(zbuf, W2b, b2, htl, t0p, t1p, ybuf, outh);
    k_gemm_z<<<g, 256, 0, stream>>>(ybuf, W1z, wt, b1, t0p, t1p, 0.5f, zbuf);
    k_gemm_k<3><<<g, 256, 0, stream>>>(zbuf, W2b, b2, htl, t0p, t1p, ybuf, outh);
    k_gemm_z<<<g, 256, 0, stream>>>(ybuf, W1z, wt, b1, t0p, t1p, 1.0f, zbuf);
    k_gemm_k<4><<<g, 256, 0, stream>>>(zbuf, W2b, b2, htl, t0p, t1p, ybuf, outh);
}

// Round 2
// 349.143 us; speedup vs baseline: 1.0889x; 1.0889x over previous
//
#include <hip/hip_runtime.h>

// ---------------- types ----------------
typedef short           s16x8 __attribute__((ext_vector_type(8)));
typedef unsigned short  u16;
typedef unsigned short  u16x8 __attribute__((ext_vector_type(8)));
typedef float           f32x4 __attribute__((ext_vector_type(4)));

// ---------------- dims ----------------
#define DB   8192
#define DI   256
#define DH   1024
#define D4H  4096
#define KXH  1280   // I + H

// ---------------- helpers ----------------
__device__ __forceinline__ u16 f2bf(float f) {
    unsigned u = __float_as_uint(f);
    u = (u + 0x7FFFu + ((u >> 16) & 1u)) >> 16;
    return (u16)u;
}
__device__ __forceinline__ float bf2f(u16 v) {
    return __uint_as_float(((unsigned)v) << 16);
}
__device__ __forceinline__ float rcp_(float x) { return __builtin_amdgcn_rcpf(x); }
__device__ __forceinline__ float sigmoid_(float x) {
    x = fminf(fmaxf(x, -30.f), 30.f);
    return rcp_(1.0f + __expf(-x));
}
__device__ __forceinline__ float tanh_(float x) {
    x = fminf(fmaxf(x, -15.f), 15.f);
    float e = __expf(2.0f * x);
    return (e - 1.0f) * rcp_(e + 1.0f);
}
__device__ __forceinline__ void gload16(const void* g, void* l) {
    __builtin_amdgcn_global_load_lds(
        (const __attribute__((address_space(1))) unsigned int*)g,
        (__attribute__((address_space(3))) unsigned int*)l, 16, 0, 0);
}

// ---------------- GEMM core (m97-structure, verified R1: ~970 TF) ----------
// C[128x128] tile = A[m0.., K] * Bw[n0.., K]^T   (both bf16, K-contiguous rows)
// 256 threads = 4 waves in 2x2; each wave 64x64 via 4x4 frags of 16x16x32 MFMA.
// LDS tiles [128][64] bf16, XOR-swizzled (c8 ^= row&7) on both stage-source and
// ds_read so ds_read_b128 is bank-conflict-free (R1: SQ_LDS_BANK_CONFLICT == 0).
template<int KTOT>
__device__ __forceinline__ void gemm_tile(
    const u16* __restrict__ A, int lda,
    const u16* __restrict__ Bw, int ldb,
    int m0, int n0, u16* As, u16* Bs, f32x4 acc[4][4])
{
    const int t    = threadIdx.x;
    const int lane = t & 63;
    const int w    = t >> 6;
    const int wrr  = (w >> 1) * 64;
    const int wcc  = (w & 1) * 64;

    const int rr  = t >> 3;                 // 0..31  (+ q*32)
    const int sc8 = (t & 7) ^ (rr & 7);
    const u16* gA = A  + (size_t)(m0 + rr) * lda + sc8 * 8;
    const u16* gB = Bw + (size_t)(n0 + rr) * ldb + sc8 * 8;
    u16* lA = As + (size_t)w * 64 * 8;      // wave-uniform LDS base (+q*2048 elems)
    u16* lB = Bs + (size_t)w * 64 * 8;

    const int l15 = lane & 15;
    const int lg  = lane >> 4;
    const int swz = l15 & 7;
    const char* cA = (const char*)As;
    const char* cB = (const char*)Bs;
    const int roA = (wrr + l15) * 128;      // row byte offset (128 B rows)
    const int roB = (wcc + l15) * 128;
    const int c0  = ((0 + lg) ^ swz) * 16;  // ks=0 swizzled 16B window
    const int c1  = ((4 + lg) ^ swz) * 16;  // ks=1

    for (int kt = 0; kt < KTOT; kt += 64) {
#pragma unroll
        for (int q = 0; q < 4; ++q)
            gload16(gA + (size_t)q * 32 * lda, lA + q * 2048);
#pragma unroll
        for (int q = 0; q < 4; ++q)
            gload16(gB + (size_t)q * 32 * ldb, lB + q * 2048);
        gA += 64; gB += 64;
        __syncthreads();   // compiler drains vmcnt before s_barrier

#pragma unroll
        for (int ks = 0; ks < 2; ++ks) {
            const int cc = ks ? c1 : c0;
            s16x8 av[4], bv[4];
#pragma unroll
            for (int mi = 0; mi < 4; ++mi)
                av[mi] = *(const s16x8*)(cA + roA + mi * 2048 + cc);
#pragma unroll
            for (int ni = 0; ni < 4; ++ni)
                bv[ni] = *(const s16x8*)(cB + roB + ni * 2048 + cc);
#pragma unroll
            for (int mi = 0; mi < 4; ++mi)
#pragma unroll
                for (int ni = 0; ni < 4; ++ni)
                    acc[mi][ni] = __builtin_amdgcn_mfma_f32_16x16x32_bf16(
                        av[mi], bv[ni], acc[mi][ni], 0, 0, 0);
        }
        __syncthreads();
    }
}

#define GEMM_PROLOGUE()                                            \
    __shared__ u16 As[128 * 64], Bs[128 * 64];                     \
    f32x4 acc[4][4];                                               \
    {   f32x4 z4 = {0.f, 0.f, 0.f, 0.f};                           \
        _Pragma("unroll") for (int i = 0; i < 4; ++i)              \
        _Pragma("unroll") for (int j = 0; j < 4; ++j)              \
            acc[i][j] = z4; }                                      \
    const int m0 = blockIdx.x * 128, n0 = blockIdx.y * 128;        \
    const int lane = threadIdx.x & 63, w = threadIdx.x >> 6;       \
    const int wrr = (w >> 1) * 64, wcc = (w & 1) * 64;             \
    const int l15 = lane & 15, lg = lane >> 4;

// D[m][n]: m = m0+wrr+mi*16+lg*4+r ; n = n0+wcc+ni*16+l15   (verified m89/m91)
#define EPILOGUE_LOOP(BODY)                                        \
    _Pragma("unroll") for (int mi = 0; mi < 4; ++mi)               \
    _Pragma("unroll") for (int ni = 0; ni < 4; ++ni)               \
    _Pragma("unroll") for (int r = 0; r < 4; ++r) {                \
        const int m = m0 + wrr + mi * 16 + lg * 4 + r;             \
        const int n = n0 + wcc + ni * 16 + l15;                    \
        float v = acc[mi][ni][r];                                  \
        BODY                                                       \
    }

// ---------------- fused gates GEMM + LSTM activation ----------------
// Wg rows are gate-interleaved: permuted row n <-> original row
//   r_orig = ((n>>4)&3)*DH + (n>>6)*16 + (n&15)
// so in the C/D layout fragment ni == gate (i,f,g,o) and all 4 gates of
// hidden unit h = ((n0+wcc)>>6)*16 + l15 sit in one thread's acc[mi][0..3][r].
__global__ __launch_bounds__(256) void k_gemm_gates(
    const u16* __restrict__ xh, const u16* __restrict__ Wg,
    const float* __restrict__ bsum, const float* __restrict__ cin,
    float* __restrict__ outc, u16* __restrict__ htl)
{
    GEMM_PROLOGUE();
    gemm_tile<KXH>(xh, KXH, Wg, KXH, m0, n0, As, Bs, acc);
    const int hb = ((n0 + wcc) >> 6) * 16 + l15;   // hidden unit for this lane
    const int cb = n0 + wcc + l15;                 // permuted-bias base (+16*gate)
    const float bi = bsum[cb];
    const float bf = bsum[cb + 16];
    const float bg = bsum[cb + 32];
    const float bo = bsum[cb + 48];
#pragma unroll
    for (int mi = 0; mi < 4; ++mi)
#pragma unroll
        for (int r = 0; r < 4; ++r) {
            const int m = m0 + wrr + mi * 16 + lg * 4 + r;
            const size_t idx = (size_t)m * DH + hb;
            float iv = acc[mi][0][r] + bi;
            float fv = acc[mi][1][r] + bf;
            float gv = acc[mi][2][r] + bg;
            float ov = acc[mi][3][r] + bo;
            float cn = sigmoid_(fv) * cin[idx] + sigmoid_(iv) * tanh_(gv);
            outc[idx] = cn;
            htl[idx] = f2bf(sigmoid_(ov) * tanh_(cn));
        }
}

// ---------------- f_node GEMM kernels ----------------
__global__ __launch_bounds__(256) void k_gemm_z(
    const u16* __restrict__ Ay, const u16* __restrict__ W1z,
    const float* __restrict__ wt, const float* __restrict__ b1,
    const float* __restrict__ t0p, const float* __restrict__ t1p, float alpha,
    u16* __restrict__ z)
{
    GEMM_PROLOGUE();
    gemm_tile<DH>(Ay, DH, W1z, DH, m0, n0, As, Bs, acc);
    const float t0v = *t0p;
    const float tv  = t0v + alpha * (*t1p - t0v);
    EPILOGUE_LOOP({
        float zz = tanh_(v + b1[n] + tv * wt[n]);
        z[(size_t)m * DH + n] = f2bf(zz);
    })
}

template<int STAGE>
__global__ __launch_bounds__(256) void k_gemm_k(
    const u16* __restrict__ zin, const u16* __restrict__ W2b,
    const float* __restrict__ b2, const u16* __restrict__ htl,
    const float* __restrict__ t0p, const float* __restrict__ t1p,
    u16* __restrict__ yout, float* __restrict__ hout)
{
    GEMM_PROLOGUE();
    gemm_tile<DH>(zin, DH, W2b, DH, m0, n0, As, Bs, acc);
    const float dtv = *t1p - *t0p;
    EPILOGUE_LOOP({
        float kv = v + b2[n];
        size_t idx = (size_t)m * DH + n;
        float ht = bf2f(htl[idx]);
        if (STAGE == 1) {
            yout[idx] = f2bf(ht + 0.5f * dtv * kv);
            hout[idx] = ht + (dtv * (1.0f / 6.0f)) * kv;   // init (no read)
        } else if (STAGE == 2) {
            yout[idx] = f2bf(ht + 0.5f * dtv * kv);
            hout[idx] += (dtv * (1.0f / 3.0f)) * kv;
        } else if (STAGE == 3) {
            yout[idx] = f2bf(ht + dtv * kv);
            hout[idx] += (dtv * (1.0f / 3.0f)) * kv;
        } else {
            hout[idx] += (dtv * (1.0f / 6.0f)) * kv;
        }
    })
}

// ---------------- prep kernels ----------------
// Permuted gate-interleaved weight + combined-bias prep.
__global__ __launch_bounds__(256) void k_prep_wg(
    const float* __restrict__ Wih, const float* __restrict__ Whh,
    const float* __restrict__ bih, const float* __restrict__ bhh,
    u16* __restrict__ Wg, float* __restrict__ bsum)
{
    int idx = blockIdx.x * 256 + threadIdx.x;           // one per 8 elems
    const int NW = D4H * (KXH / 8);
    if (idx < NW) {
        int n  = idx / (KXH / 8);
        int k8 = idx - n * (KXH / 8);
        int ro = ((n >> 4) & 3) * DH + (n >> 6) * 16 + (n & 15);
        const float* s = (k8 < DI / 8) ? (Wih + (size_t)ro * DI + k8 * 8)
                                       : (Whh + (size_t)ro * DH + (k8 - DI / 8) * 8);
        f32x4 x0 = *(const f32x4*)s;
        f32x4 x1 = *(const f32x4*)(s + 4);
        u16x8 o;
#pragma unroll
        for (int e = 0; e < 4; ++e) { o[e] = f2bf(x0[e]); o[e + 4] = f2bf(x1[e]); }
        *(u16x8*)(Wg + (size_t)idx * 8) = o;
    } else if (idx < NW + D4H / 8) {
        int j = idx - NW;
#pragma unroll
        for (int e = 0; e < 8; ++e) {
            int n = j * 8 + e;
            int ro = ((n >> 4) & 3) * DH + (n >> 6) * 16 + (n & 15);
            bsum[n] = bih[ro] + bhh[ro];
        }
    }
}

__global__ __launch_bounds__(256) void k_prep_xh(
    const float* __restrict__ x, const float* __restrict__ h, u16* __restrict__ xh)
{
    int idx = blockIdx.x * 256 + threadIdx.x;
    if (idx >= DB * (KXH / 8)) return;
    int b  = idx / (KXH / 8);
    int k8 = idx - b * (KXH / 8);
    const float* s = (k8 < DI / 8) ? (x + (size_t)b * DI + k8 * 8)
                                   : (h + (size_t)b * DH + (k8 - DI / 8) * 8);
    f32x4 x0 = *(const f32x4*)s;
    f32x4 x1 = *(const f32x4*)(s + 4);
    u16x8 o;
#pragma unroll
    for (int e = 0; e < 4; ++e) { o[e] = f2bf(x0[e]); o[e + 4] = f2bf(x1[e]); }
    *(u16x8*)(xh + (size_t)idx * 8) = o;
}

__global__ __launch_bounds__(256) void k_prep_w1(
    const float* __restrict__ W1, u16* __restrict__ W1z, float* __restrict__ wt)
{
    int idx = blockIdx.x * 256 + threadIdx.x;
    const int rows = DH * (DH / 8);
    if (idx < rows) {
        int n = idx >> 7, k8 = idx & 127;
        const float* s = W1 + (size_t)n * (DH + 1) + k8 * 8;   // stride 1025: scalar loads
        u16x8 o;
#pragma unroll
        for (int e = 0; e < 8; ++e) o[e] = f2bf(s[e]);
        *(u16x8*)(W1z + (size_t)idx * 8) = o;
    } else if (idx < rows + DH / 8) {
        int j = idx - rows;
#pragma unroll
        for (int e = 0; e < 8; ++e) {
            int n = j * 8 + e;
            wt[n] = W1[(size_t)n * (DH + 1) + DH];
        }
    }
}

__global__ __launch_bounds__(256) void k_prep_w2(
    const float* __restrict__ W2, u16* __restrict__ W2b)
{
    int idx = blockIdx.x * 256 + threadIdx.x;
    if (idx >= DH * (DH / 8)) return;
    const float* s = W2 + (size_t)idx * 8;
    f32x4 x0 = *(const f32x4*)s;
    f32x4 x1 = *(const f32x4*)(s + 4);
    u16x8 o;
#pragma unroll
    for (int e = 0; e < 4; ++e) { o[e] = f2bf(x0[e]); o[e + 4] = f2bf(x1[e]); }
    *(u16x8*)(W2b + (size_t)idx * 8) = o;
}

// ---------------- launch ----------------
extern "C" void kernel_launch(void* const* d_in, const int* in_sizes, int n_in,
                              void* d_out, int out_size, void* d_ws, size_t ws_size,
                              hipStream_t stream)
{
    (void)in_sizes; (void)n_in; (void)out_size;
    const float* x_t = (const float*)d_in[0];
    const float* hin = (const float*)d_in[1];
    const float* cin = (const float*)d_in[2];
    const float* t0p = (const float*)d_in[3];
    const float* t1p = (const float*)d_in[4];
    const float* Wih = (const float*)d_in[5];
    const float* Whh = (const float*)d_in[6];
    const float* bih = (const float*)d_in[7];
    const float* bhh = (const float*)d_in[8];
    const float* W1  = (const float*)d_in[9];
    const float* b1  = (const float*)d_in[10];
    const float* W2  = (const float*)d_in[11];
    const float* b2  = (const float*)d_in[12];

    char* ws = (char*)d_ws;
    size_t off = 0;
    u16*   Wg    = (u16*)(ws + off);  off += (size_t)D4H * KXH * 2;  // 10.5 MB
    u16*   W1z   = (u16*)(ws + off);  off += (size_t)DH * DH * 2;    //  2.1 MB
    u16*   W2b   = (u16*)(ws + off);  off += (size_t)DH * DH * 2;    //  2.1 MB
    float* wt    = (float*)(ws + off); off += (size_t)DH * 4;
    float* bsum  = (float*)(ws + off); off += (size_t)D4H * 4;
    u16*   xh    = (u16*)(ws + off);  off += (size_t)DB * KXH * 2;   // 21.0 MB
    u16*   htl   = (u16*)(ws + off);  off += (size_t)DB * DH * 2;    // 16.8 MB
    u16*   ybuf  = (u16*)(ws + off);  off += (size_t)DB * DH * 2;    // 16.8 MB
    u16*   zbuf  = (u16*)(ws + off);  off += (size_t)DB * DH * 2;    // 16.8 MB
    if (ws_size < off) return;  // insufficient workspace: fail validation cleanly

    float* outh = (float*)d_out;
    float* outc = outh + (size_t)DB * DH;

    k_prep_wg<<<(D4H * (KXH / 8) + D4H / 8 + 255) / 256, 256, 0, stream>>>(
        Wih, Whh, bih, bhh, Wg, bsum);
    k_prep_w1<<<(DH * (DH / 8) + DH / 8 + 255) / 256, 256, 0, stream>>>(W1, W1z, wt);
    k_prep_w2<<<(DH * (DH / 8) + 255) / 256, 256, 0, stream>>>(W2, W2b);
    k_prep_xh<<<(DB * (KXH / 8) + 255) / 256, 256, 0, stream>>>(x_t, hin, xh);

    k_gemm_gates<<<dim3(DB / 128, D4H / 128), 256, 0, stream>>>(
        xh, Wg, bsum, cin, outc, htl);

    dim3 g(DB / 128, DH / 128);
    k_gemm_z<<<g, 256, 0, stream>>>(htl,  W1z, wt, b1, t0p, t1p, 0.0f, zbuf);
    k_gemm_k<1><<<g, 256, 0, stream>>>(zbuf, W2b, b2, htl, t0p, t1p, ybuf, outh);
    k_gemm_z<<<g, 256, 0, stream>>>(ybuf, W1z, wt, b1, t0p, t1p, 0.5f, zbuf);
    k_gemm_k<2><<<g, 256, 0, stream>>>(zbuf, W2b, b2, htl, t0p, t1p, ybuf, outh);
    k_gemm_z<<<g, 256, 0, stream>>>(ybuf, W1z, wt, b1, t0p, t1p, 0.5f, zbuf);
    k_gemm_k<3><<<g, 256, 0, stream>>>(zbuf, W2b, b2, htl, t0p, t1p, ybuf, outh);
    k_gemm_z<<<g, 256, 0, stream>>>(ybuf, W1z, wt, b1, t0p, t1p, 1.0f, zbuf);
    k_gemm_k<4><<<g, 256, 0, stream>>>(zbuf, W2b, b2, htl, t0p, t1p, ybuf, outh);
}

// Round 3
// 343.506 us; speedup vs baseline: 1.1068x; 1.0164x over previous
//
#include <hip/hip_runtime.h>

// ---------------- types ----------------
typedef short           s16x8 __attribute__((ext_vector_type(8)));
typedef unsigned short  u16;
typedef unsigned short  u16x8 __attribute__((ext_vector_type(8)));
typedef float           f32x4 __attribute__((ext_vector_type(4)));

// ---------------- dims ----------------
#define DB   8192
#define DI   256
#define DH   1024
#define D4H  4096
#define KXH  1280   // I + H

// ---------------- helpers ----------------
__device__ __forceinline__ u16 f2bf(float f) {
    unsigned u = __float_as_uint(f);
    u = (u + 0x7FFFu + ((u >> 16) & 1u)) >> 16;
    return (u16)u;
}
__device__ __forceinline__ float bf2f(u16 v) {
    return __uint_as_float(((unsigned)v) << 16);
}
__device__ __forceinline__ float rcp_(float x) { return __builtin_amdgcn_rcpf(x); }
__device__ __forceinline__ float sigmoid_(float x) {
    x = fminf(fmaxf(x, -30.f), 30.f);
    return rcp_(1.0f + __expf(-x));
}
__device__ __forceinline__ float tanh_(float x) {
    x = fminf(fmaxf(x, -15.f), 15.f);
    float e = __expf(2.0f * x);
    return (e - 1.0f) * rcp_(e + 1.0f);
}
__device__ __forceinline__ void gload16(const void* g, void* l) {
    __builtin_amdgcn_global_load_lds(
        (const __attribute__((address_space(1))) unsigned int*)g,
        (__attribute__((address_space(3))) unsigned int*)l, 16, 0, 0);
}

// ---------------- GEMM core (m97-structure, R1: ~970 TF, 0 bank conflicts) --
template<int KTOT>
__device__ __forceinline__ void gemm_tile(
    const u16* __restrict__ A, int lda,
    const u16* __restrict__ Bw, int ldb,
    int m0, int n0, u16* As, u16* Bs, f32x4 acc[4][4])
{
    const int t    = threadIdx.x;
    const int lane = t & 63;
    const int w    = t >> 6;
    const int wrr  = (w >> 1) * 64;
    const int wcc  = (w & 1) * 64;

    const int rr  = t >> 3;                 // 0..31  (+ q*32)
    const int sc8 = (t & 7) ^ (rr & 7);
    const u16* gA = A  + (size_t)(m0 + rr) * lda + sc8 * 8;
    const u16* gB = Bw + (size_t)(n0 + rr) * ldb + sc8 * 8;
    u16* lA = As + (size_t)w * 64 * 8;      // wave-uniform LDS base (+q*2048 elems)
    u16* lB = Bs + (size_t)w * 64 * 8;

    const int l15 = lane & 15;
    const int lg  = lane >> 4;
    const int swz = l15 & 7;
    const char* cA = (const char*)As;
    const char* cB = (const char*)Bs;
    const int roA = (wrr + l15) * 128;      // row byte offset (128 B rows)
    const int roB = (wcc + l15) * 128;
    const int c0  = ((0 + lg) ^ swz) * 16;  // ks=0 swizzled 16B window
    const int c1  = ((4 + lg) ^ swz) * 16;  // ks=1

    for (int kt = 0; kt < KTOT; kt += 64) {
#pragma unroll
        for (int q = 0; q < 4; ++q)
            gload16(gA + (size_t)q * 32 * lda, lA + q * 2048);
#pragma unroll
        for (int q = 0; q < 4; ++q)
            gload16(gB + (size_t)q * 32 * ldb, lB + q * 2048);
        gA += 64; gB += 64;
        __syncthreads();   // compiler drains vmcnt before s_barrier

#pragma unroll
        for (int ks = 0; ks < 2; ++ks) {
            const int cc = ks ? c1 : c0;
            s16x8 av[4], bv[4];
#pragma unroll
            for (int mi = 0; mi < 4; ++mi)
                av[mi] = *(const s16x8*)(cA + roA + mi * 2048 + cc);
#pragma unroll
            for (int ni = 0; ni < 4; ++ni)
                bv[ni] = *(const s16x8*)(cB + roB + ni * 2048 + cc);
#pragma unroll
            for (int mi = 0; mi < 4; ++mi)
#pragma unroll
                for (int ni = 0; ni < 4; ++ni)
                    acc[mi][ni] = __builtin_amdgcn_mfma_f32_16x16x32_bf16(
                        av[mi], bv[ni], acc[mi][ni], 0, 0, 0);
        }
        __syncthreads();
    }
}

#define GEMM_PROLOGUE()                                            \
    __shared__ u16 As[128 * 64], Bs[128 * 64];                     \
    f32x4 acc[4][4];                                               \
    {   f32x4 z4 = {0.f, 0.f, 0.f, 0.f};                           \
        _Pragma("unroll") for (int i = 0; i < 4; ++i)              \
        _Pragma("unroll") for (int j = 0; j < 4; ++j)              \
            acc[i][j] = z4; }                                      \
    const int m0 = blockIdx.x * 128, n0 = blockIdx.y * 128;        \
    const int lane = threadIdx.x & 63, w = threadIdx.x >> 6;       \
    const int wrr = (w >> 1) * 64, wcc = (w & 1) * 64;             \
    const int l15 = lane & 15, lg = lane >> 4;

// D[m][n]: m = m0+wrr+mi*16+lg*4+r ; n = n0+wcc+ni*16+l15   (verified m89/m91)
// Chunked per-mi with sched_barrier(0) to cap epilogue register liveness
// (R2 lesson: unchunked fused epilogue ballooned VGPR 84->112, occupancy -26%).
#define EPILOGUE_LOOP(BODY)                                        \
    _Pragma("unroll") for (int mi = 0; mi < 4; ++mi) {             \
    _Pragma("unroll") for (int ni = 0; ni < 4; ++ni)               \
    _Pragma("unroll") for (int r = 0; r < 4; ++r) {                \
        const int m = m0 + wrr + mi * 16 + lg * 4 + r;             \
        const int n = n0 + wcc + ni * 16 + l15;                    \
        float v = acc[mi][ni][r];                                  \
        BODY                                                       \
    }                                                              \
    __builtin_amdgcn_sched_barrier(0); }

// ---------------- fused gates GEMM + LSTM activation ----------------
// Wg rows gate-interleaved: permuted row n <-> orig ((n>>4)&3)*DH+(n>>6)*16+(n&15)
// => fragment ni == gate (i,f,g,o); all 4 gates of hidden unit
// hb = ((n0+wcc)>>6)*16+l15 sit in one thread's acc[mi][0..3][r].
__global__ __launch_bounds__(256) void k_gemm_gates(
    const u16* __restrict__ xh, const u16* __restrict__ Wg,
    const float* __restrict__ bsum, const float* __restrict__ cin,
    float* __restrict__ outc, u16* __restrict__ htl)
{
    GEMM_PROLOGUE();
    gemm_tile<KXH>(xh, KXH, Wg, KXH, m0, n0, As, Bs, acc);
    const int hb = ((n0 + wcc) >> 6) * 16 + l15;   // hidden unit for this lane
    const int cb = n0 + wcc + l15;                 // permuted-bias base (+16*gate)
    const float bi = bsum[cb];
    const float bf = bsum[cb + 16];
    const float bg = bsum[cb + 32];
    const float bo = bsum[cb + 48];
#pragma unroll
    for (int mi = 0; mi < 4; ++mi) {
#pragma unroll
        for (int r = 0; r < 4; ++r) {
            const int m = m0 + wrr + mi * 16 + lg * 4 + r;
            const size_t idx = (size_t)m * DH + hb;
            float iv = acc[mi][0][r] + bi;
            float fv = acc[mi][1][r] + bf;
            float gv = acc[mi][2][r] + bg;
            float ov = acc[mi][3][r] + bo;
            float cn = sigmoid_(fv) * cin[idx] + sigmoid_(iv) * tanh_(gv);
            outc[idx] = cn;
            htl[idx] = f2bf(sigmoid_(ov) * tanh_(cn));
        }
        __builtin_amdgcn_sched_barrier(0);   // cap liveness per 16-output chunk
    }
}

// ---------------- f_node GEMM kernels ----------------
__global__ __launch_bounds__(256) void k_gemm_z(
    const u16* __restrict__ Ay, const u16* __restrict__ W1z,
    const float* __restrict__ wt, const float* __restrict__ b1,
    const float* __restrict__ t0p, const float* __restrict__ t1p, float alpha,
    u16* __restrict__ z)
{
    GEMM_PROLOGUE();
    gemm_tile<DH>(Ay, DH, W1z, DH, m0, n0, As, Bs, acc);
    const float t0v = *t0p;
    const float tv  = t0v + alpha * (*t1p - t0v);
    EPILOGUE_LOOP({
        float zz = tanh_(v + b1[n] + tv * wt[n]);
        z[(size_t)m * DH + n] = f2bf(zz);
    })
}

template<int STAGE>
__global__ __launch_bounds__(256) void k_gemm_k(
    const u16* __restrict__ zin, const u16* __restrict__ W2b,
    const float* __restrict__ b2, const u16* __restrict__ htl,
    const float* __restrict__ t0p, const float* __restrict__ t1p,
    u16* __restrict__ yout, float* __restrict__ hout)
{
    GEMM_PROLOGUE();
    gemm_tile<DH>(zin, DH, W2b, DH, m0, n0, As, Bs, acc);
    const float dtv = *t1p - *t0p;
    EPILOGUE_LOOP({
        float kv = v + b2[n];
        size_t idx = (size_t)m * DH + n;
        float ht = bf2f(htl[idx]);
        if (STAGE == 1) {
            yout[idx] = f2bf(ht + 0.5f * dtv * kv);
            hout[idx] = ht + (dtv * (1.0f / 6.0f)) * kv;   // init (no read)
        } else if (STAGE == 2) {
            yout[idx] = f2bf(ht + 0.5f * dtv * kv);
            hout[idx] += (dtv * (1.0f / 3.0f)) * kv;
        } else if (STAGE == 3) {
            yout[idx] = f2bf(ht + dtv * kv);
            hout[idx] += (dtv * (1.0f / 3.0f)) * kv;
        } else {
            hout[idx] += (dtv * (1.0f / 6.0f)) * kv;
        }
    })
}

// ---------------- merged prep kernel ----------------
// Ranges: [0,NW) Wg | [.,+NBS) bsum | [.,+NR1) W1z | [.,+NWT) wt
//         [.,+NW2) W2b | [.,+NXH) xh
#define NW   (D4H * (KXH / 8))
#define NBS  (D4H / 8)
#define NR1  (DH * (DH / 8))
#define NWT  (DH / 8)
#define NW2  (DH * (DH / 8))
#define NXH  (DB * (KXH / 8))
#define NPREP (NW + NBS + NR1 + NWT + NW2 + NXH)

__global__ __launch_bounds__(256) void k_prep_all(
    const float* __restrict__ x, const float* __restrict__ h,
    const float* __restrict__ Wih, const float* __restrict__ Whh,
    const float* __restrict__ bih, const float* __restrict__ bhh,
    const float* __restrict__ W1, const float* __restrict__ W2,
    u16* __restrict__ Wg, float* __restrict__ bsum,
    u16* __restrict__ W1z, float* __restrict__ wt,
    u16* __restrict__ W2b, u16* __restrict__ xh)
{
    int idx = blockIdx.x * 256 + threadIdx.x;
    if (idx < NW) {                                     // gate-interleaved Wg
        int n  = idx / (KXH / 8);
        int k8 = idx - n * (KXH / 8);
        int ro = ((n >> 4) & 3) * DH + (n >> 6) * 16 + (n & 15);
        const float* s = (k8 < DI / 8) ? (Wih + (size_t)ro * DI + k8 * 8)
                                       : (Whh + (size_t)ro * DH + (k8 - DI / 8) * 8);
        f32x4 x0 = *(const f32x4*)s;
        f32x4 x1 = *(const f32x4*)(s + 4);
        u16x8 o;
#pragma unroll
        for (int e = 0; e < 4; ++e) { o[e] = f2bf(x0[e]); o[e + 4] = f2bf(x1[e]); }
        *(u16x8*)(Wg + (size_t)idx * 8) = o;
        return;
    }
    idx -= NW;
    if (idx < NBS) {                                    // permuted combined bias
#pragma unroll
        for (int e = 0; e < 8; ++e) {
            int n = idx * 8 + e;
            int ro = ((n >> 4) & 3) * DH + (n >> 6) * 16 + (n & 15);
            bsum[n] = bih[ro] + bhh[ro];
        }
        return;
    }
    idx -= NBS;
    if (idx < NR1) {                                    // W1 (first DH cols)
        int n = idx >> 7, k8 = idx & 127;
        const float* s = W1 + (size_t)n * (DH + 1) + k8 * 8;  // stride 1025
        u16x8 o;
#pragma unroll
        for (int e = 0; e < 8; ++e) o[e] = f2bf(s[e]);
        *(u16x8*)(W1z + (size_t)idx * 8) = o;
        return;
    }
    idx -= NR1;
    if (idx < NWT) {                                    // W1 time column
#pragma unroll
        for (int e = 0; e < 8; ++e) {
            int n = idx * 8 + e;
            wt[n] = W1[(size_t)n * (DH + 1) + DH];
        }
        return;
    }
    idx -= NWT;
    if (idx < NW2) {                                    // W2
        const float* s = W2 + (size_t)idx * 8;
        f32x4 x0 = *(const f32x4*)s;
        f32x4 x1 = *(const f32x4*)(s + 4);
        u16x8 o;
#pragma unroll
        for (int e = 0; e < 4; ++e) { o[e] = f2bf(x0[e]); o[e + 4] = f2bf(x1[e]); }
        *(u16x8*)(W2b + (size_t)idx * 8) = o;
        return;
    }
    idx -= NW2;
    if (idx < NXH) {                                    // xh concat
        int b  = idx / (KXH / 8);
        int k8 = idx - b * (KXH / 8);
        const float* s = (k8 < DI / 8) ? (x + (size_t)b * DI + k8 * 8)
                                       : (h + (size_t)b * DH + (k8 - DI / 8) * 8);
        f32x4 x0 = *(const f32x4*)s;
        f32x4 x1 = *(const f32x4*)(s + 4);
        u16x8 o;
#pragma unroll
        for (int e = 0; e < 4; ++e) { o[e] = f2bf(x0[e]); o[e + 4] = f2bf(x1[e]); }
        *(u16x8*)(xh + (size_t)idx * 8) = o;
    }
}

// ---------------- launch ----------------
extern "C" void kernel_launch(void* const* d_in, const int* in_sizes, int n_in,
                              void* d_out, int out_size, void* d_ws, size_t ws_size,
                              hipStream_t stream)
{
    (void)in_sizes; (void)n_in; (void)out_size;
    const float* x_t = (const float*)d_in[0];
    const float* hin = (const float*)d_in[1];
    const float* cin = (const float*)d_in[2];
    const float* t0p = (const float*)d_in[3];
    const float* t1p = (const float*)d_in[4];
    const float* Wih = (const float*)d_in[5];
    const float* Whh = (const float*)d_in[6];
    const float* bih = (const float*)d_in[7];
    const float* bhh = (const float*)d_in[8];
    const float* W1  = (const float*)d_in[9];
    const float* b1  = (const float*)d_in[10];
    const float* W2  = (const float*)d_in[11];
    const float* b2  = (const float*)d_in[12];

    char* ws = (char*)d_ws;
    size_t off = 0;
    u16*   Wg    = (u16*)(ws + off);  off += (size_t)D4H * KXH * 2;  // 10.5 MB
    u16*   W1z   = (u16*)(ws + off);  off += (size_t)DH * DH * 2;    //  2.1 MB
    u16*   W2b   = (u16*)(ws + off);  off += (size_t)DH * DH * 2;    //  2.1 MB
    float* wt    = (float*)(ws + off); off += (size_t)DH * 4;
    float* bsum  = (float*)(ws + off); off += (size_t)D4H * 4;
    u16*   xh    = (u16*)(ws + off);  off += (size_t)DB * KXH * 2;   // 21.0 MB
    u16*   htl   = (u16*)(ws + off);  off += (size_t)DB * DH * 2;    // 16.8 MB
    u16*   ybuf  = (u16*)(ws + off);  off += (size_t)DB * DH * 2;    // 16.8 MB
    u16*   zbuf  = (u16*)(ws + off);  off += (size_t)DB * DH * 2;    // 16.8 MB
    if (ws_size < off) return;  // insufficient workspace: fail validation cleanly

    float* outh = (float*)d_out;
    float* outc = outh + (size_t)DB * DH;

    k_prep_all<<<(NPREP + 255) / 256, 256, 0, stream>>>(
        x_t, hin, Wih, Whh, bih, bhh, W1, W2, Wg, bsum, W1z, wt, W2b, xh);

    k_gemm_gates<<<dim3(DB / 128, D4H / 128), 256, 0, stream>>>(
        xh, Wg, bsum, cin, outc, htl);

    dim3 g(DB / 128, DH / 128);
    k_gemm_z<<<g, 256, 0, stream>>>(htl,  W1z, wt, b1, t0p, t1p, 0.0f, zbuf);
    k_gemm_k<1><<<g, 256, 0, stream>>>(zbuf, W2b, b2, htl, t0p, t1p, ybuf, outh);
    k_gemm_z<<<g, 256, 0, stream>>>(ybuf, W1z, wt, b1, t0p, t1p, 0.5f, zbuf);
    k_gemm_k<2><<<g, 256, 0, stream>>>(zbuf, W2b, b2, htl, t0p, t1p, ybuf, outh);
    k_gemm_z<<<g, 256, 0, stream>>>(ybuf, W1z, wt, b1, t0p, t1p, 0.5f, zbuf);
    k_gemm_k<3><<<g, 256, 0, stream>>>(zbuf, W2b, b2, htl, t0p, t1p, ybuf, outh);
    k_gemm_z<<<g, 256, 0, stream>>>(ybuf, W1z, wt, b1, t0p, t1p, 1.0f, zbuf);
    k_gemm_k<4><<<g, 256, 0, stream>>>(zbuf, W2b, b2, htl, t0p, t1p, ybuf, outh);
}